// Round 2
// baseline (248.428 us; speedup 1.0000x reference)
//
#include <hip/hip_runtime.h>

// LaBramChannelPatcher: [B=16, W=32, T=1000, C=64] fp32 ->
//   patches [B, W, C*nt=320, P=200]  (== per-(b,w) transpose [T,C] -> [C,T])
//   channel_indices [320] = repeat(arange(64), 5)
//   time_indices    [320] = tile(arange(5), 64)
//
// Memory-bound transpose: LDS-tiled, coalesced on both sides.

#define TDIM 1000
#define CDIM 64
#define TT   100        // t-rows per tile (1000 = 10 * 100)
#define LSTR 65         // LDS row stride (odd -> conflict-free column reads)
#define NTILE 10
#define PATCH_ELEMS 32768000   // 16*32*320*200

__global__ __launch_bounds__(256) void labram_patcher_kernel(
    const float* __restrict__ in, float* __restrict__ out)
{
    __shared__ float lds[TT * LSTR];   // lds[ti][c], stride 65 words

    const int tid  = threadIdx.x;
    const int tile = blockIdx.x % NTILE;
    const int bw   = blockIdx.x / NTILE;   // 0..511  (b*32 + w)
    const int t0   = tile * TT;

    // ---- Phase 1: coalesced float4 loads along C, scatter into lds[ti][c] ----
    // 100 rows x 16 float4/row = 1600 float4 loads per block.
    const float4* in4 = (const float4*)in + (size_t)(bw * TDIM + t0) * (CDIM / 4);
    for (int i = tid; i < TT * 16; i += 256) {
        int ti = i >> 4;        // 0..99
        int c4 = i & 15;        // 0..15
        float4 v = in4[ti * 16 + c4];
        int base = ti * LSTR + c4 * 4;
        lds[base + 0] = v.x;
        lds[base + 1] = v.y;
        lds[base + 2] = v.z;
        lds[base + 3] = v.w;
    }
    __syncthreads();

    // ---- Phase 2: gather 4 consecutive-t scalars per lane, coalesced float4
    //      store along t. 64 c-rows x 25 float4/row = 1600 stores per block. ----
    for (int i = tid; i < CDIM * 25; i += 256) {
        int c  = i / 25;
        int j  = i - c * 25;
        int ti = j * 4;
        float4 v;
        v.x = lds[(ti + 0) * LSTR + c];
        v.y = lds[(ti + 1) * LSTR + c];
        v.z = lds[(ti + 2) * LSTR + c];
        v.w = lds[(ti + 3) * LSTR + c];
        size_t off = (size_t)(bw * CDIM + c) * TDIM + (t0 + ti);
        *(float4*)(out + off) = v;
    }

    // ---- Index outputs (tiny): block 0 only, grid-stride over 320 entries ----
    if (blockIdx.x == 0) {
        for (int i = tid; i < 320; i += 256) {
            out[PATCH_ELEMS + i]       = (float)(i / 5);  // channel_indices
            out[PATCH_ELEMS + 320 + i] = (float)(i % 5);  // time_indices
        }
    }
}

extern "C" void kernel_launch(void* const* d_in, const int* in_sizes, int n_in,
                              void* d_out, int out_size, void* d_ws, size_t ws_size,
                              hipStream_t stream) {
    const float* in = (const float*)d_in[0];
    float* out = (float*)d_out;
    // 512 (b,w) slices * 10 t-tiles
    dim3 grid(512 * NTILE);
    dim3 block(256);
    labram_patcher_kernel<<<grid, block, 0, stream>>>(in, out);
}